// Round 4
// baseline (154.699 us; speedup 1.0000x reference)
//
#include <hip/hip_runtime.h>
#include <hip/hip_bf16.h>

// out[b, l, c] = data[(cycle_index[b] % CYC + l) % CYC, c]
// B=4096, L=720, C=64 fp32. ~755MB pure streaming writes -> write-BW bound.
// R4: one block per batch row b (grid-stride). cycle_index load + %168 are
// hoisted out of the inner loop; modular index maintained incrementally
// (no div/mod in the loop). Inner loop: 1 L1/L2 table load + 1 NT dwordx4
// store + ~5 VALU. Each block writes 180KB contiguous per b.

typedef float f4_t __attribute__((ext_vector_type(4)));

#define B_      4096
#define L_      720
#define C4_     16        // 64 floats / 4
#define CYC_    168
#define LPB_    16        // l-values per wave-pass (256 thr = 16 l x 16 c4)
#define CHUNKS_ (L_ / LPB_)          // 45 (exact)

__global__ __launch_bounds__(256) void rc_kernel_fixed(
    const int* __restrict__ cycle_index,
    const f4_t* __restrict__ data4,    // [CYC][C4]
    f4_t* __restrict__ out4)           // [B][L][C4]
{
    const int t    = threadIdx.x;
    const int lofs = t >> 4;            // 0..15
    const int c4   = t & 15;            // 0..15

    for (int b = blockIdx.x; b < B_; b += gridDim.x) {
        const int start = cycle_index[b] % CYC_;   // once per 180KB written

        int src = start + lofs;                    // < 184
        if (src >= CYC_) src -= CYC_;

        f4_t* outp = out4 + (size_t)b * (L_ * C4_) + t;

        #pragma unroll 5
        for (int it = 0; it < CHUNKS_; ++it) {
            const f4_t v = data4[src * C4_ + c4];  // L1/L2-resident table
            __builtin_nontemporal_store(v, outp);
            src += LPB_;                           // incremental mod-168
            if (src >= CYC_) src -= CYC_;
            outp += 256;                           // next 4KB block-chunk
        }
    }
}

// Generic fallback (any B/L): same structure, runtime bounds.
__global__ __launch_bounds__(256) void rc_kernel_generic(
    const int* __restrict__ cycle_index,
    const f4_t* __restrict__ data4,
    f4_t* __restrict__ out4,
    int B, int L)
{
    const int t    = threadIdx.x;
    const int lofs = t >> 4;
    const int c4   = t & 15;

    for (int b = blockIdx.x; b < B; b += gridDim.x) {
        const int start = cycle_index[b] % CYC_;

        int src = start + lofs;
        if (src >= CYC_) src -= CYC_;

        f4_t* outp = out4 + (size_t)b * (size_t)(L * C4_) + t;

        int l = lofs;
        for (; l < L; l += LPB_) {
            const f4_t v = data4[src * C4_ + c4];
            __builtin_nontemporal_store(v, outp);
            src += LPB_;
            if (src >= CYC_) src -= CYC_;
            outp += 256;
        }
    }
}

extern "C" void kernel_launch(void* const* d_in, const int* in_sizes, int n_in,
                              void* d_out, int out_size, void* d_ws, size_t ws_size,
                              hipStream_t stream) {
    const int*   cycle_index = (const int*)d_in[0];
    const float* data        = (const float*)d_in[2];

    const int B = in_sizes[0];
    const int L = out_size / (B * 64);

    const int grid = 2048;  // 256 CU x 8 blocks; 2 b's per block at B=4096

    if (B == B_ && L == L_) {
        rc_kernel_fixed<<<grid, 256, 0, stream>>>(
            cycle_index, (const f4_t*)data, (f4_t*)d_out);
    } else {
        rc_kernel_generic<<<grid, 256, 0, stream>>>(
            cycle_index, (const f4_t*)data, (f4_t*)d_out, B, L);
    }
}

// Round 5
// 154.249 us; speedup vs baseline: 1.0029x; 1.0029x over previous
//
#include <hip/hip_runtime.h>
#include <hip/hip_bf16.h>

// out[b, l, c] = data[(cycle_index[b] % CYC + l) % CYC, c]
// B=4096, L=720, C=64 fp32. ~755MB pure streaming writes -> write-BW bound.
// R5: register-preload. src_k = (start + lofs + 16k) % 168 has PERIOD 21
// (16*21 = 336 = 2*168), so each thread's 45 stores draw from only 21
// distinct float4 values. Preload them into registers (fully unrolled,
// compile-time indices -> no scratch), then the store loop is pure
// reg->NT-store with zero load dependence -- same structure as the
// 6.7 TB/s fillBuffer kernel.

typedef float f4_t __attribute__((ext_vector_type(4)));

#define B_      4096
#define L_      720
#define C4_     16        // 64 floats / 4
#define CYC_    168
#define LPB_    16        // l-values per block-pass (256 thr = 16 l x 16 c4)
#define CHUNKS_ (L_ / LPB_)          // 45 (exact)
#define PERIOD_ 21                   // stride-16 cycle length mod 168

__global__ __launch_bounds__(256) void rc_kernel_fixed(
    const int* __restrict__ cycle_index,
    const f4_t* __restrict__ data4,    // [CYC][C4]
    f4_t* __restrict__ out4)           // [B][L][C4]
{
    const int t    = threadIdx.x;
    const int lofs = t >> 4;            // 0..15
    const int c4   = t & 15;            // 0..15

    for (int b = blockIdx.x; b < B_; b += gridDim.x) {
        const int start = cycle_index[b] % CYC_;

        int src = start + lofs;                    // < 184
        if (src >= CYC_) src -= CYC_;

        // Preload the 21-periodic table values for this (b, lofs, c4).
        f4_t r[PERIOD_];
        #pragma unroll
        for (int j = 0; j < PERIOD_; ++j) {
            r[j] = data4[src * C4_ + c4];          // L1-resident 43KB table
            src += LPB_;
            if (src >= CYC_) src -= CYC_;
        }

        // Pure store stream: 45 independent NT dwordx4, no load deps.
        f4_t* outp = out4 + (size_t)b * (L_ * C4_) + t;
        #pragma unroll
        for (int k = 0; k < CHUNKS_; ++k) {
            __builtin_nontemporal_store(r[k % PERIOD_], outp);
            outp += 256;                           // +4KB per block-pass
        }
    }
}

// Generic fallback (any B/L): R4 structure, runtime bounds.
__global__ __launch_bounds__(256) void rc_kernel_generic(
    const int* __restrict__ cycle_index,
    const f4_t* __restrict__ data4,
    f4_t* __restrict__ out4,
    int B, int L)
{
    const int t    = threadIdx.x;
    const int lofs = t >> 4;
    const int c4   = t & 15;

    for (int b = blockIdx.x; b < B; b += gridDim.x) {
        const int start = cycle_index[b] % CYC_;

        int src = start + lofs;
        if (src >= CYC_) src -= CYC_;

        f4_t* outp = out4 + (size_t)b * (size_t)(L * C4_) + t;

        for (int l = lofs; l < L; l += LPB_) {
            const f4_t v = data4[src * C4_ + c4];
            __builtin_nontemporal_store(v, outp);
            src += LPB_;
            if (src >= CYC_) src -= CYC_;
            outp += 256;
        }
    }
}

extern "C" void kernel_launch(void* const* d_in, const int* in_sizes, int n_in,
                              void* d_out, int out_size, void* d_ws, size_t ws_size,
                              hipStream_t stream) {
    const int*   cycle_index = (const int*)d_in[0];
    const float* data        = (const float*)d_in[2];

    const int B = in_sizes[0];
    const int L = out_size / (B * 64);

    const int grid = 2048;  // 256 CU x 8 blocks; 2 b's per block at B=4096

    if (B == B_ && L == L_) {
        rc_kernel_fixed<<<grid, 256, 0, stream>>>(
            cycle_index, (const f4_t*)data, (f4_t*)d_out);
    } else {
        rc_kernel_generic<<<grid, 256, 0, stream>>>(
            cycle_index, (const f4_t*)data, (f4_t*)d_out, B, L);
    }
}

// Round 6
// 120.125 us; speedup vs baseline: 1.2878x; 1.2841x over previous
//
#include <hip/hip_runtime.h>
#include <hip/hip_bf16.h>

// out[b, l, c] = data[(cycle_index[b] % CYC + l) % CYC, c]
// B=4096, L=720, C=64 fp32. ~755MB pure streaming writes -> write-BW bound.
// R6: exact A/B vs R3 (150.5us): same chunk-interleaved grid-stride
// structure, PLAIN stores instead of nontemporal. Theory: fill kernel's
// 6.7TB/s goes through L2 (write-allocate + coalesced drain); gfx950 NT
// path plateaus at ~5TB/s. Chunk interleave keeps the whole grid writing
// one contiguous ~8MB sliding window (HBM row-buffer friendly).

typedef float f4_t __attribute__((ext_vector_type(4)));

#define B_      4096
#define L_      720
#define C4_     16        // 64 floats / 4
#define CYC_    168
#define LPB_    16        // l-values per chunk
#define CHUNKS_ (L_ / LPB_)          // 45 (exact)
#define NCHUNK_ (B_ * CHUNKS_)       // 184320

__global__ __launch_bounds__(256) void rc_kernel_fixed(
    const int* __restrict__ cycle_index,
    const f4_t* __restrict__ data4,    // [CYC][C4]
    f4_t* __restrict__ out4)           // [B][L][C4]
{
    const int t    = threadIdx.x;
    const int lofs = t >> 4;            // 0..15
    const int c4   = t & 15;            // 0..15

    for (int chunk = blockIdx.x; chunk < NCHUNK_; chunk += gridDim.x) {
        const int b  = chunk / CHUNKS_;          // const divisor -> magic mul
        const int lc = chunk - b * CHUNKS_;
        const int l  = lc * LPB_ + lofs;

        const int start = cycle_index[b] % CYC_; // uniform per iteration
        int src = start + l;                     // < CYC_ + L_
        src %= CYC_;                             // const divisor -> magic mul

        const f4_t v = data4[src * C4_ + c4];    // L1/L2-resident 43KB table
        out4[((size_t)b * L_ + l) * C4_ + c4] = v;   // PLAIN store (through L2)
    }
}

// Generic fallback (any B/L), grid-stride, plain stores.
__global__ __launch_bounds__(256) void rc_kernel_generic(
    const int* __restrict__ cycle_index,
    const f4_t* __restrict__ data4,
    f4_t* __restrict__ out4,
    int L, int chunks, int nchunk_total)
{
    const int t    = threadIdx.x;
    const int lofs = t >> 4;
    const int c4   = t & 15;

    for (int chunk = blockIdx.x; chunk < nchunk_total; chunk += gridDim.x) {
        const int b  = chunk / chunks;
        const int lc = chunk - b * chunks;
        const int l  = lc * LPB_ + lofs;
        if (l >= L) continue;

        const int start = cycle_index[b] % CYC_;
        int src = start + l;
        src %= CYC_;

        const f4_t v = data4[src * C4_ + c4];
        out4[((size_t)b * (size_t)L + l) * C4_ + c4] = v;
    }
}

extern "C" void kernel_launch(void* const* d_in, const int* in_sizes, int n_in,
                              void* d_out, int out_size, void* d_ws, size_t ws_size,
                              hipStream_t stream) {
    const int*   cycle_index = (const int*)d_in[0];
    const float* data        = (const float*)d_in[2];

    const int B = in_sizes[0];
    const int L = out_size / (B * 64);

    const int grid = 2048;  // 256 CU x 8 blocks, grid-stride

    if (B == B_ && L == L_) {
        rc_kernel_fixed<<<grid, 256, 0, stream>>>(
            cycle_index, (const f4_t*)data, (f4_t*)d_out);
    } else {
        const int chunks = (L + LPB_ - 1) / LPB_;
        const int nchunk = B * chunks;
        rc_kernel_generic<<<grid, 256, 0, stream>>>(
            cycle_index, (const f4_t*)data, (f4_t*)d_out,
            L, chunks, nchunk);
    }
}